// Round 1
// baseline (1108.678 us; speedup 1.0000x reference)
//
#include <hip/hip_runtime.h>
#include <math.h>

#define N_NODES 50000
#define N_EDGES 800000

// ---------------- K1: node GEMM  X(N x 64) @ W(64 x 64) + b -> Q/K/V -------
// grid (782, 3): blockIdx.y selects matrix; 64 nodes per block, 256 threads.
__global__ __launch_bounds__(256) void node_gemm(
    const float* __restrict__ x,
    const float* __restrict__ Wq, const float* __restrict__ bq,
    const float* __restrict__ Wk, const float* __restrict__ bk,
    const float* __restrict__ Wv, const float* __restrict__ bv,
    float* __restrict__ Qo, float* __restrict__ Ko, float* __restrict__ Vo)
{
    const int c = blockIdx.y;
    const float* W = (c == 0) ? Wq : (c == 1) ? Wk : Wv;
    const float* b = (c == 0) ? bq : (c == 1) ? bk : bv;
    float* outp    = (c == 0) ? Qo : (c == 1) ? Ko : Vo;

    __shared__ float Xs[64][68];   // +4 pad: 4-rows-apart -> bank offset 16 (2-way, free)
    __shared__ float Ws[64][64];
    const int t  = threadIdx.x;
    const int n0 = blockIdx.x * 64;

    // stage X tile (guard rows past N)
    for (int i = 0; i < 4; i++) {
        int fi = t + i * 256;           // float4 index among 1024
        int row = fi >> 4, c4 = (fi & 15) * 4;
        float4 v = make_float4(0.f, 0.f, 0.f, 0.f);
        if (n0 + row < N_NODES) v = *(const float4*)&x[(size_t)(n0 + row) * 64 + c4];
        *(float4*)&Xs[row][c4] = v;
    }
    // stage W tile
    for (int i = 0; i < 4; i++) {
        int fi = t + i * 256;
        int row = fi >> 4, c4 = (fi & 15) * 4;
        *(float4*)&Ws[row][c4] = *(const float4*)&W[(size_t)row * 64 + c4];
    }
    __syncthreads();

    const int tx = t & 15, ty = t >> 4;
    float acc[4][4] = {};
    #pragma unroll
    for (int k4 = 0; k4 < 64; k4 += 4) {
        float4 xv[4], wv[4];
        #pragma unroll
        for (int r = 0; r < 4; r++) xv[r] = *(const float4*)&Xs[ty * 4 + r][k4];
        #pragma unroll
        for (int j = 0; j < 4; j++) wv[j] = *(const float4*)&Ws[k4 + j][tx * 4];
        #pragma unroll
        for (int r = 0; r < 4; r++) {
            acc[r][0] += xv[r].x * wv[0].x + xv[r].y * wv[1].x + xv[r].z * wv[2].x + xv[r].w * wv[3].x;
            acc[r][1] += xv[r].x * wv[0].y + xv[r].y * wv[1].y + xv[r].z * wv[2].y + xv[r].w * wv[3].y;
            acc[r][2] += xv[r].x * wv[0].z + xv[r].y * wv[1].z + xv[r].z * wv[2].z + xv[r].w * wv[3].z;
            acc[r][3] += xv[r].x * wv[0].w + xv[r].y * wv[1].w + xv[r].z * wv[2].w + xv[r].w * wv[3].w;
        }
    }
    float4 bb = *(const float4*)&b[tx * 4];
    #pragma unroll
    for (int r = 0; r < 4; r++) {
        int row = n0 + ty * 4 + r;
        if (row < N_NODES) {
            float4 o;
            o.x = acc[r][0] + bb.x; o.y = acc[r][1] + bb.y;
            o.z = acc[r][2] + bb.z; o.w = acc[r][3] + bb.w;
            *(float4*)&outp[(size_t)row * 64 + tx * 4] = o;
        }
    }
}

// ---------------- sort-by-dst machinery -----------------------------------
__global__ void hist_kernel(const int* __restrict__ edge_index, int* __restrict__ counts)
{
    int e = blockIdx.x * 256 + threadIdx.x;
    if (e < N_EDGES) atomicAdd(&counts[edge_index[N_EDGES + e]], 1);
}

__global__ __launch_bounds__(1024) void scan_kernel(
    const int* __restrict__ counts, int* __restrict__ offsets, int* __restrict__ cursor)
{
    const int CH = 49;                      // 1024*49 >= 50000
    __shared__ int part[1024];
    int t = threadIdx.x;
    int base = t * CH;
    int s = 0;
    for (int j = 0; j < CH; j++) { int idx = base + j; if (idx < N_NODES) s += counts[idx]; }
    part[t] = s;
    __syncthreads();
    for (int off = 1; off < 1024; off <<= 1) {
        int v = (t >= off) ? part[t - off] : 0;
        __syncthreads();
        part[t] += v;
        __syncthreads();
    }
    int run = part[t] - s;                  // exclusive prefix of this chunk
    for (int j = 0; j < CH; j++) {
        int idx = base + j;
        if (idx < N_NODES) { offsets[idx] = run; cursor[idx] = run; run += counts[idx]; }
    }
    if (t == 0) offsets[N_NODES] = part[1023];
}

__global__ void scatter_kernel(const int* __restrict__ edge_index, int* __restrict__ cursor,
                               int* __restrict__ sorted_eid, int* __restrict__ sorted_src)
{
    int e = blockIdx.x * 256 + threadIdx.x;
    if (e < N_EDGES) {
        int dst = edge_index[N_EDGES + e];
        int pos = atomicAdd(&cursor[dst], 1);
        sorted_eid[pos] = e;
        sorted_src[pos] = edge_index[e];
    }
}

// ---------------- K5: fused edge kernel ------------------------------------
// Per edge: E = edge_attr @ We + be; score = relu(signed_sqrt((K[src]+Q[dst])*E_w)+E_b);
// write wE; a = sum_d score*Aw, clip, exp -> expa.  One wave = 4 edges.
__global__ __launch_bounds__(256) void edge_kernel(
    const float* __restrict__ edge_attr,
    const int*   __restrict__ edge_index,
    const float* __restrict__ We, const float* __restrict__ be,
    const float* __restrict__ Aw,
    const float* __restrict__ Qws, const float* __restrict__ Kws,
    float* __restrict__ wE, float* __restrict__ expa)
{
    __shared__ float WeS[64][128];     // 32 KB, staged once per block
    __shared__ float beS[128];
    __shared__ float Es[4][4][128];    // [wave][edge][col]
    const int t = threadIdx.x;
    for (int i = 0; i < 8; i++) {
        int fi = t + i * 256;                   // of 2048 float4
        int row = fi >> 5, c4 = (fi & 31) * 4;
        *(float4*)&WeS[row][c4] = *(const float4*)&We[(size_t)row * 128 + c4];
    }
    if (t < 32) *(float4*)&beS[t * 4] = *(const float4*)&be[t * 4];
    __syncthreads();

    const int lane = t & 63;
    const int wid  = __builtin_amdgcn_readfirstlane(t >> 6);
    const int e0   = blockIdx.x * 16 + wid * 4;     // wave-uniform
    const float* ea0 = edge_attr + (size_t)e0 * 64; // uniform -> s_load broadcasts
    const float* ea1 = ea0 + 64;
    const float* ea2 = ea0 + 128;
    const float* ea3 = ea0 + 192;

    float acc[4][2] = {};
    const int l2 = lane * 2;
    #pragma unroll 8
    for (int k = 0; k < 64; k++) {
        float2 w = *(const float2*)&WeS[k][l2];
        float a0 = ea0[k], a1 = ea1[k], a2 = ea2[k], a3 = ea3[k];
        acc[0][0] += a0 * w.x; acc[0][1] += a0 * w.y;
        acc[1][0] += a1 * w.x; acc[1][1] += a1 * w.y;
        acc[2][0] += a2 * w.x; acc[2][1] += a2 * w.y;
        acc[3][0] += a3 * w.x; acc[3][1] += a3 * w.y;
    }
    float b0 = beS[l2], b1 = beS[l2 + 1];
    #pragma unroll
    for (int e = 0; e < 4; e++) {
        float2 o; o.x = acc[e][0] + b0; o.y = acc[e][1] + b1;
        *(float2*)&Es[wid][e][l2] = o;   // same-wave LDS: in-order, no barrier needed
    }

    const int h = lane >> 3, d = lane & 7;
    const float aw = Aw[d * 8 + h];      // Aw (D,H,1): [d][h]
    #pragma unroll
    for (int e = 0; e < 4; e++) {
        int ge  = e0 + e;
        int src = edge_index[ge];
        int dst = edge_index[N_EDGES + ge];
        float Ew = Es[wid][e][h * 16 + d];
        float Eb = Es[wid][e][h * 16 + 8 + d];
        float kq = Kws[(size_t)src * 64 + lane] + Qws[(size_t)dst * 64 + lane];
        float v  = kq * Ew;
        float sc = copysignf(sqrtf(fabsf(v)), v) + Eb;
        sc = fmaxf(sc, 0.0f);
        wE[(size_t)ge * 64 + lane] = sc;
        float ap = sc * aw;
        ap += __shfl_xor(ap, 1);
        ap += __shfl_xor(ap, 2);
        ap += __shfl_xor(ap, 4);            // sum over d within 8-lane head group
        ap = fminf(fmaxf(ap, -5.0f), 5.0f);
        float ex = __expf(ap);
        if (d == 0) expa[(size_t)ge * 8 + h] = ex;
    }
}

// ---------------- K6: per-node gather (atomic-free) -------------------------
// One wave per node; lane = h*8+d. Accumulate s, sum(exp*V), sum(exp*e_t);
// epilogue applies VeRow and divides by s.
__global__ __launch_bounds__(256) void gather_kernel(
    const int* __restrict__ offsets,
    const int* __restrict__ sorted_eid,
    const int* __restrict__ sorted_src,
    const float* __restrict__ expa,
    const float* __restrict__ wE,
    const float* __restrict__ Vws,
    const float* __restrict__ VeRow,
    float* __restrict__ hout)
{
    const int t = threadIdx.x;
    const int lane = t & 63;
    const int wid  = __builtin_amdgcn_readfirstlane(t >> 6);
    const int n = blockIdx.x * 4 + wid;
    const int h = lane >> 3;
    const int start = offsets[n], end = offsets[n + 1];

    float s_acc = 0.f, wv = 0.f, rv = 0.f;
    for (int i = start; i < end; i++) {
        int eid = sorted_eid[i];
        int src = sorted_src[i];
        float ex = expa[(size_t)eid * 8 + h];
        float w  = wE[(size_t)eid * 64 + lane];
        float v  = Vws[(size_t)src * 64 + lane];
        s_acc += ex;
        wv += ex * v;
        rv += ex * w;
    }
    // rvt[h,c] = sum_d rv(h,d) * VeRow[d][h][c]; this lane is (h, c=lane&7)
    float rvt = 0.f;
    int gbase = lane & ~7;
    #pragma unroll
    for (int d2 = 0; d2 < 8; d2++) {
        float rvd = __shfl(rv, gbase + d2);
        rvt += rvd * VeRow[d2 * 64 + h * 8 + (lane & 7)];
    }
    float inv = 1.0f / (s_acc + 1e-16f);
    hout[(size_t)n * 64 + lane] = (wv + rvt) * inv;
}

// ---------------- launch ----------------------------------------------------
extern "C" void kernel_launch(void* const* d_in, const int* in_sizes, int n_in,
                              void* d_out, int out_size, void* d_ws, size_t ws_size,
                              hipStream_t stream)
{
    const float* x         = (const float*)d_in[0];
    const float* edge_attr = (const float*)d_in[1];
    const int*   edge_index= (const int*)  d_in[2];
    const float* Wq = (const float*)d_in[3];  const float* bq = (const float*)d_in[4];
    const float* Wk = (const float*)d_in[5];  const float* bk = (const float*)d_in[6];
    const float* We = (const float*)d_in[7];  const float* be = (const float*)d_in[8];
    const float* Wv = (const float*)d_in[9];  const float* bv = (const float*)d_in[10];
    const float* Aw = (const float*)d_in[11]; const float* VeRow = (const float*)d_in[12];

    float* hout = (float*)d_out;                       // (N, 64)
    float* wE   = hout + (size_t)N_NODES * 64;         // (E, 64)

    float* Q    = (float*)d_ws;
    float* K    = Q + (size_t)N_NODES * 64;
    float* V    = K + (size_t)N_NODES * 64;
    float* expa = V + (size_t)N_NODES * 64;            // (E, 8)
    int* ip         = (int*)(expa + (size_t)N_EDGES * 8);
    int* counts     = ip;
    int* offsets    = counts + N_NODES;                // N+1 entries
    int* cursor     = offsets + N_NODES + 1;
    int* sorted_eid = cursor + N_NODES;
    int* sorted_src = sorted_eid + N_EDGES;

    hipMemsetAsync(counts, 0, N_NODES * sizeof(int), stream);
    node_gemm<<<dim3(782, 3), 256, 0, stream>>>(x, Wq, bq, Wk, bk, Wv, bv, Q, K, V);
    hist_kernel<<<(N_EDGES + 255) / 256, 256, 0, stream>>>(edge_index, counts);
    scan_kernel<<<1, 1024, 0, stream>>>(counts, offsets, cursor);
    scatter_kernel<<<(N_EDGES + 255) / 256, 256, 0, stream>>>(edge_index, cursor, sorted_eid, sorted_src);
    edge_kernel<<<N_EDGES / 16, 256, 0, stream>>>(edge_attr, edge_index, We, be, Aw, Q, K, wE, expa);
    gather_kernel<<<N_NODES / 4, 256, 0, stream>>>(offsets, sorted_eid, sorted_src, expa, wE, V, VeRow, hout);
}

// Round 2
// 915.730 us; speedup vs baseline: 1.2107x; 1.2107x over previous
//
#include <hip/hip_runtime.h>
#include <math.h>

#define N_NODES 50000
#define N_EDGES 800000
#define EDGE_BLOCKS 2500
#define TILES_PER_BLOCK 5      // 2500 * 5 * 64 = 800000 edges

typedef __attribute__((ext_vector_type(8))) short short8;   // 8 bf16 (4 VGPRs)
typedef __attribute__((ext_vector_type(4))) float f32x4;

__device__ inline unsigned short bf16_rne(float x) {
    unsigned u = __float_as_uint(x);
    unsigned r = u + 0x7FFFu + ((u >> 16) & 1u);
    return (unsigned short)(r >> 16);
}
__device__ inline float bf16_to_f32(unsigned short h) {
    return __uint_as_float(((unsigned)h) << 16);
}

// ---------------- K1: node GEMM  X(N x 64) @ W(64 x 64) + b -> Q/K/V -------
__global__ __launch_bounds__(256) void node_gemm(
    const float* __restrict__ x,
    const float* __restrict__ Wq, const float* __restrict__ bq,
    const float* __restrict__ Wk, const float* __restrict__ bk,
    const float* __restrict__ Wv, const float* __restrict__ bv,
    float* __restrict__ Qo, float* __restrict__ Ko, float* __restrict__ Vo)
{
    const int c = blockIdx.y;
    const float* W = (c == 0) ? Wq : (c == 1) ? Wk : Wv;
    const float* b = (c == 0) ? bq : (c == 1) ? bk : bv;
    float* outp    = (c == 0) ? Qo : (c == 1) ? Ko : Vo;

    __shared__ float Xs[64][68];
    __shared__ float Ws[64][64];
    const int t  = threadIdx.x;
    const int n0 = blockIdx.x * 64;

    for (int i = 0; i < 4; i++) {
        int fi = t + i * 256;
        int row = fi >> 4, c4 = (fi & 15) * 4;
        float4 v = make_float4(0.f, 0.f, 0.f, 0.f);
        if (n0 + row < N_NODES) v = *(const float4*)&x[(size_t)(n0 + row) * 64 + c4];
        *(float4*)&Xs[row][c4] = v;
    }
    for (int i = 0; i < 4; i++) {
        int fi = t + i * 256;
        int row = fi >> 4, c4 = (fi & 15) * 4;
        *(float4*)&Ws[row][c4] = *(const float4*)&W[(size_t)row * 64 + c4];
    }
    __syncthreads();

    const int tx = t & 15, ty = t >> 4;
    float acc[4][4] = {};
    #pragma unroll
    for (int k4 = 0; k4 < 64; k4 += 4) {
        float4 xv[4], wv[4];
        #pragma unroll
        for (int r = 0; r < 4; r++) xv[r] = *(const float4*)&Xs[ty * 4 + r][k4];
        #pragma unroll
        for (int j = 0; j < 4; j++) wv[j] = *(const float4*)&Ws[k4 + j][tx * 4];
        #pragma unroll
        for (int r = 0; r < 4; r++) {
            acc[r][0] += xv[r].x * wv[0].x + xv[r].y * wv[1].x + xv[r].z * wv[2].x + xv[r].w * wv[3].x;
            acc[r][1] += xv[r].x * wv[0].y + xv[r].y * wv[1].y + xv[r].z * wv[2].y + xv[r].w * wv[3].y;
            acc[r][2] += xv[r].x * wv[0].z + xv[r].y * wv[1].z + xv[r].z * wv[2].z + xv[r].w * wv[3].z;
            acc[r][3] += xv[r].x * wv[0].w + xv[r].y * wv[1].w + xv[r].z * wv[2].w + xv[r].w * wv[3].w;
        }
    }
    float4 bb = *(const float4*)&b[tx * 4];
    #pragma unroll
    for (int r = 0; r < 4; r++) {
        int row = n0 + ty * 4 + r;
        if (row < N_NODES) {
            float4 o;
            o.x = acc[r][0] + bb.x; o.y = acc[r][1] + bb.y;
            o.z = acc[r][2] + bb.z; o.w = acc[r][3] + bb.w;
            *(float4*)&outp[(size_t)row * 64 + tx * 4] = o;
        }
    }
}

// ---------------- sort-by-dst machinery -----------------------------------
__global__ void hist_kernel(const int* __restrict__ edge_index, int* __restrict__ counts)
{
    int e = blockIdx.x * 256 + threadIdx.x;
    if (e < N_EDGES) atomicAdd(&counts[edge_index[N_EDGES + e]], 1);
}

__global__ __launch_bounds__(1024) void scan_kernel(
    const int* __restrict__ counts, int* __restrict__ offsets, int* __restrict__ cursor)
{
    const int CH = 49;
    __shared__ int part[1024];
    int t = threadIdx.x;
    int base = t * CH;
    int s = 0;
    for (int j = 0; j < CH; j++) { int idx = base + j; if (idx < N_NODES) s += counts[idx]; }
    part[t] = s;
    __syncthreads();
    for (int off = 1; off < 1024; off <<= 1) {
        int v = (t >= off) ? part[t - off] : 0;
        __syncthreads();
        part[t] += v;
        __syncthreads();
    }
    int run = part[t] - s;
    for (int j = 0; j < CH; j++) {
        int idx = base + j;
        if (idx < N_NODES) { offsets[idx] = run; cursor[idx] = run; run += counts[idx]; }
    }
    if (t == 0) offsets[N_NODES] = part[1023];
}

__global__ void scatter_kernel(const int* __restrict__ edge_index, int* __restrict__ cursor,
                               int2* __restrict__ sorted_es)
{
    int e = blockIdx.x * 256 + threadIdx.x;
    if (e < N_EDGES) {
        int dst = edge_index[N_EDGES + e];
        int pos = atomicAdd(&cursor[dst], 1);
        sorted_es[pos] = make_int2(e, edge_index[e]);
    }
}

// ---------------- K5: MFMA edge kernel -------------------------------------
// E = edge_attr @ We + be via split-bf16 MFMA (Ahi*Whi + Alo*Whi + Ahi*Wlo);
// epilogue: score = relu(signed_sqrt((K[src]+Q[dst])*E_w)+E_b) -> wE (coalesced).
// LDS: Bfrag 32KB (frag-ordered, conflict-free b128 reads) + 17KB union
// {A-frags | kq/score buffer}.  50.2KB -> 3 blocks/CU.
__global__ __launch_bounds__(256, 3) void edge_kernel(
    const float* __restrict__ edge_attr,
    const int*   __restrict__ edge_index,
    const float* __restrict__ We, const float* __restrict__ be,
    const float* __restrict__ Qws, const float* __restrict__ Kws,
    float* __restrict__ wE)
{
    __shared__ __align__(16) unsigned short Bf[16384];   // [hl][j][c][lane][8] = 32KB
    __shared__ __align__(16) unsigned char  UB[17408];   // union: Af 16KB | kq 64x68 f32
    unsigned short* Af  = (unsigned short*)UB;
    float*          kqs = (float*)UB;

    const int t    = threadIdx.x;
    const int lane = t & 63;
    const int w    = t >> 6;
    const int n    = lane & 15;
    const int q    = lane >> 4;
    const int d    = n & 7;

    // ---- stage We -> Bf (hi/lo, fragment-ordered), once per block ----
    for (int i = 0; i < 8; i++) {
        int fi = t + i * 256;                    // 2048 float4 of We(64x128)
        int k  = fi >> 5;
        int n4 = (fi & 31) * 4;
        float4 v4 = *(const float4*)&We[(size_t)k * 128 + n4];
        int c = k >> 5, qq = (k >> 3) & 3, jj = k & 7;
        float vv[4] = {v4.x, v4.y, v4.z, v4.w};
        #pragma unroll
        for (int u = 0; u < 4; u++) {
            int nn = n4 + u;
            int j  = nn >> 4;
            int ln = qq * 16 + (nn & 15);
            unsigned short hi = bf16_rne(vv[u]);
            unsigned short lo = bf16_rne(vv[u] - bf16_to_f32(hi));
            Bf[((0 * 8 + j) * 2 + c) * 512 + ln * 8 + jj] = hi;
            Bf[((1 * 8 + j) * 2 + c) * 512 + ln * 8 + jj] = lo;
        }
    }
    float bev[8];
    #pragma unroll
    for (int j = 0; j < 8; j++) bev[j] = be[j * 16 + n];

    for (int it = 0; it < TILES_PER_BLOCK; it++) {
        const int tile  = blockIdx.x + it * EDGE_BLOCKS;
        const int ebase = tile * 64;

        __syncthreads();   // prev epilogue LDS reads done; Bf visible (1st iter)

        // ---- stage A tile (64 edges x 64 k) as hi/lo fragments ----
        for (int i = 0; i < 4; i++) {
            int fi  = t + i * 256;               // 1024 float4
            int row = fi >> 4;
            int c4  = (fi & 15) * 4;
            float4 v4 = *(const float4*)&edge_attr[(size_t)(ebase + row) * 64 + c4];
            int ww = row >> 4, mm = row & 15;
            int c = c4 >> 5, qq = (c4 >> 3) & 3, j0 = c4 & 7;
            float vv[4] = {v4.x, v4.y, v4.z, v4.w};
            unsigned short hi[4], lo[4];
            #pragma unroll
            for (int u = 0; u < 4; u++) {
                hi[u] = bf16_rne(vv[u]);
                lo[u] = bf16_rne(vv[u] - bf16_to_f32(hi[u]));
            }
            int base_us = (qq * 16 + mm) * 8 + j0;
            *(ushort4*)&Af[((0 * 4 + ww) * 2 + c) * 512 + base_us] = make_ushort4(hi[0], hi[1], hi[2], hi[3]);
            *(ushort4*)&Af[((1 * 4 + ww) * 2 + c) * 512 + base_us] = make_ushort4(lo[0], lo[1], lo[2], lo[3]);
        }
        __syncthreads();   // A staged

        short8 ah0 = *(const short8*)&Af[((0 * 4 + w) * 2 + 0) * 512 + lane * 8];
        short8 ah1 = *(const short8*)&Af[((0 * 4 + w) * 2 + 1) * 512 + lane * 8];
        short8 al0 = *(const short8*)&Af[((1 * 4 + w) * 2 + 0) * 512 + lane * 8];
        short8 al1 = *(const short8*)&Af[((1 * 4 + w) * 2 + 1) * 512 + lane * 8];

        __syncthreads();   // A frags in regs -> union becomes kq buffer

        // ---- stage kq = K[src] + Q[dst]  (coalesced 256B/row gathers) ----
        for (int i = 0; i < 4; i++) {
            int fi  = t + i * 256;
            int row = fi >> 4;
            int c4  = (fi & 15) * 4;
            int ge  = ebase + row;
            int s_  = edge_index[ge];
            int d_  = edge_index[N_EDGES + ge];
            float4 kv = *(const float4*)&Kws[(size_t)s_ * 64 + c4];
            float4 qv = *(const float4*)&Qws[(size_t)d_ * 64 + c4];
            float4 o;
            o.x = kv.x + qv.x; o.y = kv.y + qv.y; o.z = kv.z + qv.z; o.w = kv.w + qv.w;
            *(float4*)&kqs[row * 68 + c4] = o;
        }

        // ---- MFMA: acc[j] over 8 n-tiles, 2 K-chunks, 3 split products ----
        f32x4 acc[8];
        #pragma unroll
        for (int j = 0; j < 8; j++) acc[j] = (f32x4){0.f, 0.f, 0.f, 0.f};
        #pragma unroll
        for (int j = 0; j < 8; j++) {
            short8 bh0 = *(const short8*)&Bf[((0 * 8 + j) * 2 + 0) * 512 + lane * 8];
            short8 bh1 = *(const short8*)&Bf[((0 * 8 + j) * 2 + 1) * 512 + lane * 8];
            short8 bl0 = *(const short8*)&Bf[((1 * 8 + j) * 2 + 0) * 512 + lane * 8];
            short8 bl1 = *(const short8*)&Bf[((1 * 8 + j) * 2 + 1) * 512 + lane * 8];
            acc[j] = __builtin_amdgcn_mfma_f32_16x16x32_bf16(ah0, bh0, acc[j], 0, 0, 0);
            acc[j] = __builtin_amdgcn_mfma_f32_16x16x32_bf16(ah1, bh1, acc[j], 0, 0, 0);
            acc[j] = __builtin_amdgcn_mfma_f32_16x16x32_bf16(al0, bh0, acc[j], 0, 0, 0);
            acc[j] = __builtin_amdgcn_mfma_f32_16x16x32_bf16(al1, bh1, acc[j], 0, 0, 0);
            acc[j] = __builtin_amdgcn_mfma_f32_16x16x32_bf16(ah0, bl0, acc[j], 0, 0, 0);
            acc[j] = __builtin_amdgcn_mfma_f32_16x16x32_bf16(ah1, bl1, acc[j], 0, 0, 0);
        }
        __syncthreads();   // kq staged by all threads

        // ---- epilogue: scores; write back into kq slots (own-wave rows) ----
        #pragma unroll
        for (int j = 0; j < 8; j++) {
            #pragma unroll
            for (int r = 0; r < 4; r++) {
                int e_loc = w * 16 + q * 4 + r;
                float Ev = acc[j][r] + bev[j];
                float pv = __shfl_xor(Ev, 8);
                float ew = (n < 8) ? Ev : pv;     // E_w[d]
                float eb = (n < 8) ? pv : Ev;     // E_b[d]
                float kq = kqs[e_loc * 68 + j * 8 + d];
                float v  = kq * ew;
                float sc = copysignf(sqrtf(fabsf(v)), v) + eb;
                sc = fmaxf(sc, 0.0f);
                kqs[e_loc * 68 + j * 8 + d] = sc; // dup lanes write same value
            }
        }
        // coalesced wE store (same-wave LDS data: in-order, no barrier)
        #pragma unroll
        for (int i = 0; i < 4; i++) {
            int e_loc = w * 16 + i * 4 + q;
            float4 o = *(const float4*)&kqs[e_loc * 68 + n * 4];
            *(float4*)&wE[(size_t)(ebase + e_loc) * 64 + n * 4] = o;
        }
    }
}

// ---------------- K6: per-node gather (atomic-free, exp recomputed) --------
__global__ __launch_bounds__(256) void gather_kernel(
    const int*  __restrict__ offsets,
    const int2* __restrict__ sorted_es,
    const float* __restrict__ wE,
    const float* __restrict__ Vws,
    const float* __restrict__ Aw,
    const float* __restrict__ VeRow,
    float* __restrict__ hout)
{
    const int t = threadIdx.x;
    const int lane = t & 63;
    const int w = t >> 6;
    const int node = blockIdx.x * 4 + w;
    const int h = lane >> 3, dd = lane & 7;
    const float aw = Aw[dd * 8 + h];
    const int start = offsets[node], end = offsets[node + 1];

    float s_acc = 0.f, wv = 0.f, rv = 0.f;
    int i = start;
    for (; i + 1 < end; i += 2) {
        int2 es0 = sorted_es[i];
        int2 es1 = sorted_es[i + 1];
        float w0 = wE[(size_t)es0.x * 64 + lane];
        float v0 = Vws[(size_t)es0.y * 64 + lane];
        float w1 = wE[(size_t)es1.x * 64 + lane];
        float v1 = Vws[(size_t)es1.y * 64 + lane];
        float t0 = w0 * aw;
        t0 += __shfl_xor(t0, 1); t0 += __shfl_xor(t0, 2); t0 += __shfl_xor(t0, 4);
        float t1 = w1 * aw;
        t1 += __shfl_xor(t1, 1); t1 += __shfl_xor(t1, 2); t1 += __shfl_xor(t1, 4);
        t0 = fminf(fmaxf(t0, -5.0f), 5.0f);
        t1 = fminf(fmaxf(t1, -5.0f), 5.0f);
        float e0 = __expf(t0), e1 = __expf(t1);
        s_acc += e0 + e1;
        wv += e0 * v0 + e1 * v1;
        rv += e0 * w0 + e1 * w1;
    }
    if (i < end) {
        int2 es0 = sorted_es[i];
        float w0 = wE[(size_t)es0.x * 64 + lane];
        float v0 = Vws[(size_t)es0.y * 64 + lane];
        float t0 = w0 * aw;
        t0 += __shfl_xor(t0, 1); t0 += __shfl_xor(t0, 2); t0 += __shfl_xor(t0, 4);
        t0 = fminf(fmaxf(t0, -5.0f), 5.0f);
        float e0 = __expf(t0);
        s_acc += e0; wv += e0 * v0; rv += e0 * w0;
    }
    float rvt = 0.f;
    int gbase = lane & ~7;
    #pragma unroll
    for (int d2 = 0; d2 < 8; d2++) {
        float rvd = __shfl(rv, gbase + d2);
        rvt += rvd * VeRow[d2 * 64 + h * 8 + dd];
    }
    float inv = 1.0f / (s_acc + 1e-16f);
    hout[(size_t)node * 64 + lane] = (wv + rvt) * inv;
}

// ---------------- launch ----------------------------------------------------
extern "C" void kernel_launch(void* const* d_in, const int* in_sizes, int n_in,
                              void* d_out, int out_size, void* d_ws, size_t ws_size,
                              hipStream_t stream)
{
    const float* x         = (const float*)d_in[0];
    const float* edge_attr = (const float*)d_in[1];
    const int*   edge_index= (const int*)  d_in[2];
    const float* Wq = (const float*)d_in[3];  const float* bq = (const float*)d_in[4];
    const float* Wk = (const float*)d_in[5];  const float* bk = (const float*)d_in[6];
    const float* We = (const float*)d_in[7];  const float* be = (const float*)d_in[8];
    const float* Wv = (const float*)d_in[9];  const float* bv = (const float*)d_in[10];
    const float* Aw = (const float*)d_in[11]; const float* VeRow = (const float*)d_in[12];

    float* hout = (float*)d_out;                       // (N, 64)
    float* wE   = hout + (size_t)N_NODES * 64;         // (E, 64)

    float* Q = (float*)d_ws;
    float* K = Q + (size_t)N_NODES * 64;
    float* V = K + (size_t)N_NODES * 64;
    int* counts     = (int*)(V + (size_t)N_NODES * 64);
    int* offsets    = counts + N_NODES;                // N+1 entries
    int* cursor     = offsets + N_NODES + 1;
    int2* sorted_es = (int2*)(cursor + N_NODES + 1);   // +1 pads int2 to 8B alignment

    hipMemsetAsync(counts, 0, N_NODES * sizeof(int), stream);
    node_gemm<<<dim3(782, 3), 256, 0, stream>>>(x, Wq, bq, Wk, bk, Wv, bv, Q, K, V);
    hist_kernel<<<(N_EDGES + 255) / 256, 256, 0, stream>>>(edge_index, counts);
    scan_kernel<<<1, 1024, 0, stream>>>(counts, offsets, cursor);
    scatter_kernel<<<(N_EDGES + 255) / 256, 256, 0, stream>>>(edge_index, cursor, sorted_es);
    edge_kernel<<<EDGE_BLOCKS, 256, 0, stream>>>(edge_attr, edge_index, We, be, Q, K, wE);
    gather_kernel<<<N_NODES / 4, 256, 0, stream>>>(offsets, sorted_es, wE, V, Aw, VeRow, hout);
}